// Round 15
// baseline (249.214 us; speedup 1.0000x reference)
//
#include <hip/hip_runtime.h>
#include <hip/hip_bf16.h>

#define BB   128
#define DDIM 256
#define HH   4
#define NNN  256
#define MMM  256

typedef __hip_bfloat16 bf16;
typedef short  short8   __attribute__((ext_vector_type(8)));
typedef unsigned short ushort8_t __attribute__((ext_vector_type(8)));
typedef float  f32x4    __attribute__((ext_vector_type(4)));
typedef float  f32x2    __attribute__((ext_vector_type(2)));

// ---------------- helpers ----------------
__device__ __forceinline__ unsigned short f2bf(float x) {       // RNE f32->bf16
    unsigned u = __builtin_bit_cast(unsigned, x);
    u += 0x7FFFu + ((u >> 16) & 1u);
    return (unsigned short)(u >> 16);
}
__device__ __forceinline__ float bf2f(unsigned short b) {
    unsigned u = ((unsigned)b) << 16;
    return __builtin_bit_cast(float, u);
}

// transpose a 4x4 f32 tile held across 4 consecutive lanes (p = lane&3).
__device__ __forceinline__ void xpose4(float v[4], const int p) {
    float ta = __shfl_xor((p & 1) ? v[0] : v[1], 1, 64);
    float tb = __shfl_xor((p & 1) ? v[2] : v[3], 1, 64);
    float u0 = (p & 1) ? ta : v[0];
    float u1 = (p & 1) ? v[1] : ta;
    float u2 = (p & 1) ? tb : v[2];
    float u3 = (p & 1) ? v[3] : tb;
    float tc = __shfl_xor((p & 2) ? u0 : u2, 2, 64);
    float td = __shfl_xor((p & 2) ? u1 : u3, 2, 64);
    v[0] = (p & 2) ? tc : u0;
    v[1] = (p & 2) ? td : u1;
    v[2] = (p & 2) ? u2 : tc;
    v[3] = (p & 2) ? u3 : td;
}

// 3-level bf16 split to 3 planes 8192 B apart (attn Q/K staging)
__device__ __forceinline__ void split3_store8k(char* dst, const float v[4]) {
    unsigned short h[4], m[4], l[4];
    #pragma unroll
    for (int i = 0; i < 4; ++i) {
        h[i] = f2bf(v[i]);
        float r1 = v[i] - bf2f(h[i]);
        m[i] = f2bf(r1);
        float r2 = r1 - bf2f(m[i]);
        l[i] = f2bf(r2);
    }
    uint2 hp, mp, lp;
    hp.x = (unsigned)h[0] | ((unsigned)h[1] << 16);
    hp.y = (unsigned)h[2] | ((unsigned)h[3] << 16);
    mp.x = (unsigned)m[0] | ((unsigned)m[1] << 16);
    mp.y = (unsigned)m[2] | ((unsigned)m[3] << 16);
    lp.x = (unsigned)l[0] | ((unsigned)l[1] << 16);
    lp.y = (unsigned)l[2] | ((unsigned)l[3] << 16);
    *(uint2*)dst = hp;
    *(uint2*)(dst + 8192) = mp;
    *(uint2*)(dst + 16384) = lp;
}

// 2-plane split (planes 16384 B apart): hi/mid   (projm)
__device__ __forceinline__ void split2_store(char* dst, const float v[4]) {
    unsigned short h[4], m[4];
    #pragma unroll
    for (int i = 0; i < 4; ++i) {
        h[i] = f2bf(v[i]);
        float r1 = v[i] - bf2f(h[i]);
        m[i] = f2bf(r1);
    }
    uint2 hp, mp;
    hp.x = (unsigned)h[0] | ((unsigned)h[1] << 16);
    hp.y = (unsigned)h[2] | ((unsigned)h[3] << 16);
    mp.x = (unsigned)m[0] | ((unsigned)m[1] << 16);
    mp.y = (unsigned)m[2] | ((unsigned)m[3] << 16);
    *(uint2*)dst = hp;
    *(uint2*)(dst + 16384) = mp;
}

// single-plane bf16 store (exact when v came from bf16)
__device__ __forceinline__ void split1_store(char* dst, const float v[4]) {
    uint2 hp;
    hp.x = (unsigned)f2bf(v[0]) | ((unsigned)f2bf(v[1]) << 16);
    hp.y = (unsigned)f2bf(v[2]) | ((unsigned)f2bf(v[3]) << 16);
    *(uint2*)dst = hp;
}

__device__ __forceinline__ void ldx4(const float* p, float v[4]) {
    const float4 f = *(const float4*)p;
    v[0] = f.x; v[1] = f.y; v[2] = f.z; v[3] = f.w;
}
__device__ __forceinline__ void ldx4(const bf16* p, float v[4]) {
    uint2 u = *(const uint2*)p;
    v[0] = bf2f((unsigned short)(u.x & 0xFFFF));
    v[1] = bf2f((unsigned short)(u.x >> 16));
    v[2] = bf2f((unsigned short)(u.y & 0xFFFF));
    v[3] = bf2f((unsigned short)(u.y >> 16));
}

__device__ __forceinline__ float gmax16(float v) {
    v = fmaxf(v, __shfl_xor(v, 1, 64));
    v = fmaxf(v, __shfl_xor(v, 2, 64));
    v = fmaxf(v, __shfl_xor(v, 4, 64));
    v = fmaxf(v, __shfl_xor(v, 8, 64));
    return v;
}
__device__ __forceinline__ float gsum16(float v) {
    v += __shfl_xor(v, 1, 64);
    v += __shfl_xor(v, 2, 64);
    v += __shfl_xor(v, 4, 64);
    v += __shfl_xor(v, 8, 64);
    return v;
}

// bitonic sort of 16 values, DESCENDING, fully static (80 compare-exchanges).
__device__ __forceinline__ void sort16_desc(float w[16]) {
    #pragma unroll
    for (int k = 2; k <= 16; k <<= 1) {
        #pragma unroll
        for (int j = k >> 1; j > 0; j >>= 1) {
            #pragma unroll
            for (int i = 0; i < 16; ++i) {
                const int l = i ^ j;
                if (l > i) {
                    const bool dmax = ((i & k) == 0);   // descending network
                    float mx = fmaxf(w[i], w[l]);
                    float mn = fminf(w[i], w[l]);
                    w[i] = dmax ? mx : mn;
                    w[l] = dmax ? mn : mx;
                }
            }
        }
    }
}

// ---------------------------------------------------------------------------
// f32 projection (Q AND K): plain f32 [b,e,n] output. Per output element:
// sequential FMA over f=0..255, packed f32x2 pairs (round-12/13/14 green).
// Tile 64e x 128n, 256 threads, 8e x 4n per thread, grid (2,4,128).
// ---------------------------------------------------------------------------
__global__ __launch_bounds__(256)
void proj_kernel(const float* __restrict__ X, const float* __restrict__ W,
                 const float* __restrict__ bias, float* __restrict__ Y) {
    __shared__ float Wt[32][68];    // [f_local][e_local 0..63]
    __shared__ float Xt[32][132];   // [f_local][n_local 0..127]

    const int t  = threadIdx.x;
    const int tx = t & 31;          // n sub-tile: 4n at tx*4
    const int ty = t >> 5;          // e sub-tile: 8e at ty*8
    const int n0 = blockIdx.x * 128;
    const int e0 = blockIdx.y * 64;
    const int b  = blockIdx.z;
    const size_t plane = (size_t)b * DDIM * NNN;

    f32x2 acc2[8][2];
    #pragma unroll
    for (int i = 0; i < 8; ++i) {
        acc2[i][0] = f32x2{0.f, 0.f};
        acc2[i][1] = f32x2{0.f, 0.f};
    }

    for (int f0 = 0; f0 < DDIM; f0 += 32) {
        #pragma unroll
        for (int i = 0; i < 8; ++i) {
            int idx = t + i * 256;          // 0..2047
            int fl = idx & 31, el = idx >> 5;
            Wt[fl][el] = W[(size_t)(e0 + el) * DDIM + f0 + fl];
        }
        #pragma unroll
        for (int i = 0; i < 4; ++i) {
            int idx = t + i * 256;          // 0..1023
            int fl = idx >> 5, nl4 = idx & 31;
            *(float4*)&Xt[fl][nl4 * 4] =
                *(const float4*)&X[plane + (size_t)(f0 + fl) * NNN + n0 + nl4 * 4];
        }
        __syncthreads();

        #pragma unroll
        for (int ff = 0; ff < 32; ++ff) {
            const float4 av0 = *(const float4*)&Wt[ff][ty * 8];
            const float4 av1 = *(const float4*)&Wt[ff][ty * 8 + 4];
            const float4 bv  = *(const float4*)&Xt[ff][tx * 4];
            const float a[8] = {av0.x, av0.y, av0.z, av0.w, av1.x, av1.y, av1.z, av1.w};
            const f32x2 c0 = {bv.x, bv.y};
            const f32x2 c1 = {bv.z, bv.w};
            #pragma unroll
            for (int i2 = 0; i2 < 8; ++i2) {
                const f32x2 aa = {a[i2], a[i2]};
                acc2[i2][0] = __builtin_elementwise_fma(aa, c0, acc2[i2][0]);
                acc2[i2][1] = __builtin_elementwise_fma(aa, c1, acc2[i2][1]);
            }
        }
        __syncthreads();
    }

    #pragma unroll
    for (int i2 = 0; i2 < 8; ++i2) {
        const int e = e0 + ty * 8 + i2;
        const float bs = bias[e];
        const size_t off = plane + (size_t)e * NNN + n0 + tx * 4;
        float4 o;
        o.x = acc2[i2][0].x + bs; o.y = acc2[i2][0].y + bs;
        o.z = acc2[i2][1].x + bs; o.w = acc2[i2][1].y + bs;
        *(float4*)&Y[off] = o;
    }
}

// ---------------------------------------------------------------------------
// attn5: fused attention. Round-14 green structure; K staged IN-KERNEL from
// plain f32 [b,e,n] via the round-6-green xpose4+split3 block (base 0).
// Block = (b, h, 64-row n-tile), 4 waves, LDS 32 KB, 4 blocks/CU.
// ---------------------------------------------------------------------------
__global__ __launch_bounds__(256, 4)
void attn5_kernel(const float* __restrict__ qf, const float* __restrict__ kf,
                  const bf16* __restrict__ vb, bf16* __restrict__ ob,
                  const int* __restrict__ kptr) {
    extern __shared__ __align__(16) char smem[];

    const int t    = threadIdx.x;
    const int lane = t & 63;
    const int w    = t >> 6;
    const int g    = lane >> 4;
    const int c16  = lane & 15;

    const int i    = blockIdx.x;
    const int work = (i & 7) * 256 + (i >> 3);
    const int bx = work & 3;
    const int h  = (work >> 2) & 3;
    const int b  = work >> 4;
    const int n0 = bx * 64;

    const size_t planeF = (size_t)b * DDIM * NNN;
    const size_t planeV = (size_t)b * DDIM * MMM;

    int kk = kptr[0];
    kk = kk < 1 ? 1 : (kk > MMM ? MMM : kk);

    // ---- stage Q from [b,e,n]: strided load, x0.125, xpose4, split3 ----
    {
        const int p = lane & 3, G = lane >> 2;
        #pragma unroll
        for (int it = 0; it < 4; ++it) {
            int dch = w + 4 * it;               // 0..15
            int drow = dch * 4 + p;
            float v[4];
            const float4 f4 = *(const float4*)&qf[planeF + (size_t)(drow * HH + h) * NNN + n0 + G * 4];
            v[0] = f4.x * 0.125f; v[1] = f4.y * 0.125f;
            v[2] = f4.z * 0.125f; v[3] = f4.w * 0.125f;
            xpose4(v, p);
            int nl = G * 4 + p;                 // 0..63
            int base = nl * 128 + ((dch * 8) ^ ((nl & 7) << 4));
            split3_store8k(smem + base, v);
        }
    }
    __syncthreads();

    // ---- Q A-fragments -> regs ----
    short8 qh[2], qm[2], ql[2];
    #pragma unroll
    for (int ks = 0; ks < 2; ++ks) {
        int nl = w * 16 + c16;
        int off = nl * 128 + ((ks * 64 + g * 16) ^ ((nl & 7) << 4));
        qh[ks] = *(const short8*)(smem + off);
        qm[ks] = *(const short8*)(smem + 8192 + off);
        ql[ks] = *(const short8*)(smem + 16384 + off);
    }
    __syncthreads();    // Q LDS region free for K

    // ---- scores ----
    f32x4 acc[16];
    #pragma unroll
    for (int m = 0; m < 16; ++m) acc[m] = f32x4{0.f, 0.f, 0.f, 0.f};

    #pragma unroll
    for (int tt = 0; tt < 4; ++tt) {
        if (tt) __syncthreads();            // prev tt's frag reads done
        // stage K tile [64m][64d] from f32 [b,e,n]: xpose4 + split3 (r6 green)
        {
            const int p = lane & 3, G = lane >> 2;
            #pragma unroll
            for (int it = 0; it < 4; ++it) {
                int dch = w + 4 * it;           // 0..15
                int drow = dch * 4 + p;
                int mcol = tt * 64 + G * 4;
                float v[4];
                const float4 f4 = *(const float4*)&kf[planeF + (size_t)(drow * HH + h) * MMM + mcol];
                v[0] = f4.x; v[1] = f4.y; v[2] = f4.z; v[3] = f4.w;
                xpose4(v, p);
                int ml = G * 4 + p;             // tile-local m 0..63
                int base = ml * 128 + ((dch * 8) ^ ((ml & 7) << 4));
                split3_store8k(smem + base, v);
            }
        }
        __syncthreads();

        #pragma unroll
        for (int mf = 0; mf < 4; ++mf) {
            #pragma unroll
            for (int ks = 0; ks < 2; ++ks) {
                int ml = mf * 16 + c16;
                int off = ml * 128 + ((ks * 64 + g * 16) ^ ((ml & 7) << 4));
                short8 bh_ = *(const short8*)(smem + off);
                short8 bm_ = *(const short8*)(smem + 8192 + off);
                short8 bl_ = *(const short8*)(smem + 16384 + off);
                f32x4 a = acc[tt * 4 + mf];
                a = __builtin_amdgcn_mfma_f32_16x16x32_bf16(qh[ks], bh_, a, 0, 0, 0);
                a = __builtin_amdgcn_mfma_f32_16x16x32_bf16(qh[ks], bm_, a, 0, 0, 0);
                a = __builtin_amdgcn_mfma_f32_16x16x32_bf16(qm[ks], bh_, a, 0, 0, 0);
                a = __builtin_amdgcn_mfma_f32_16x16x32_bf16(qm[ks], bm_, a, 0, 0, 0);
                a = __builtin_amdgcn_mfma_f32_16x16x32_bf16(qh[ks], bl_, a, 0, 0, 0);
                a = __builtin_amdgcn_mfma_f32_16x16x32_bf16(ql[ks], bh_, a, 0, 0, 0);
                acc[tt * 4 + mf] = a;
            }
        }
    }
    __syncthreads();    // K reads done: P region free

    // ---- top-k thresholds via per-lane descending sort + leader shift-pop ----
    float thr[4], rmx[4];
    #pragma unroll
    for (int r = 0; r < 4; ++r) {
        float s[16];
        #pragma unroll
        for (int mf = 0; mf < 16; ++mf) s[mf] = acc[mf][r];
        sort16_desc(s);
        float gm = gmax16(s[0]);
        rmx[r] = gm;
        for (int it = 1; it < kk; ++it) {
            unsigned long long bal = __ballot(s[0] == gm);
            unsigned gmask = (unsigned)((bal >> (g * 16)) & 0xFFFFull);
            int leader = __builtin_ctz(gmask);
            bool hit = (c16 == leader);
            #pragma unroll
            for (int j = 0; j < 15; ++j) s[j] = hit ? s[j + 1] : s[j];
            s[15] = hit ? -INFINITY : s[15];
            gm = gmax16(s[0]);
        }
        thr[r] = gm;
    }

    // ---- softmax (in regs) -> P [64][256] @0 ----
    #pragma unroll
    for (int mf = 0; mf < 16; ++mf) {
        #pragma unroll
        for (int r = 0; r < 4; ++r) {
            float a = acc[mf][r];
            acc[mf][r] = (a >= thr[r]) ? __expf(a - rmx[r]) : 0.f;
        }
    }
    float inv_[4];
    #pragma unroll
    for (int r = 0; r < 4; ++r) {
        float s = ((acc[0][r] + acc[1][r]) + (acc[2][r] + acc[3][r]))
                + ((acc[4][r] + acc[5][r]) + (acc[6][r] + acc[7][r]))
                + ((acc[8][r] + acc[9][r]) + (acc[10][r] + acc[11][r]))
                + ((acc[12][r] + acc[13][r]) + (acc[14][r] + acc[15][r]));
        s = gsum16(s);
        inv_[r] = 1.0f / s;
    }
    #pragma unroll
    for (int mf = 0; mf < 16; ++mf) {
        #pragma unroll
        for (int r = 0; r < 4; ++r) {
            int row = w * 16 + g * 4 + r;
            int m2  = (mf * 16 + c16) * 2;
            int off = row * 512 + (m2 ^ ((row & 7) << 4));
            *(unsigned short*)(smem + off) = f2bf(acc[mf][r] * inv_[r]);
        }
    }
    __syncthreads();

    // ---- PV: P from LDS, V B-frags DIRECT from global ----
    f32x4 o[4];
    #pragma unroll
    for (int df = 0; df < 4; ++df) o[df] = f32x4{0.f, 0.f, 0.f, 0.f};

    #pragma unroll
    for (int half = 0; half < 2; ++half) {
        short8 pa[4];
        #pragma unroll
        for (int ks = 0; ks < 4; ++ks) {
            int row = w * 16 + c16;
            int off = row * 512 + ((half * 256 + ks * 64 + g * 16) ^ ((row & 7) << 4));
            pa[ks] = *(const short8*)(smem + off);
        }
        #pragma unroll
        for (int df = 0; df < 4; ++df) {
            int d = df * 16 + c16;
            const bf16* vrow = vb + planeV + (size_t)(d * HH + h) * MMM + half * 128;
            f32x4 o_ = o[df];
            #pragma unroll
            for (int ks = 0; ks < 4; ++ks) {
                short8 vv = *(const short8*)(vrow + ks * 32 + g * 8);
                o_ = __builtin_amdgcn_mfma_f32_16x16x32_bf16(pa[ks], vv, o_, 0, 0, 0);
            }
            o[df] = o_;
        }
    }
    __syncthreads();    // P reads done; out region free

    // ---- out: frags -> [64d][64n] @0 -> global [channel][n] ----
    #pragma unroll
    for (int df = 0; df < 4; ++df)
        #pragma unroll
        for (int r = 0; r < 4; ++r) {
            int d  = df * 16 + c16;
            int nl = w * 16 + g * 4 + r;
            int off = d * 128 + ((nl * 2) ^ ((d & 7) << 4));
            *(unsigned short*)(smem + off) = f2bf(o[df][r]);
        }
    __syncthreads();
    #pragma unroll
    for (int it = 0; it < 2; ++it) {
        int idx = t + it * 256;                 // 0..511
        int d = idx >> 3, ch = idx & 7;
        int off = d * 128 + ((ch * 16) ^ ((d & 7) << 4));
        ushort8_t val = *(const ushort8_t*)(smem + off);
        *(ushort8_t*)&ob[planeV + (size_t)(d * HH + h) * NNN + n0 + ch * 8] = val;
    }
}

// ---------------------------------------------------------------------------
// MFMA projection (VALUE paths). Round-12/13/14 green, verbatim.
// ---------------------------------------------------------------------------
template <typename TIN, typename TOUT>
__global__ __launch_bounds__(512, 2)
void projm_kernel(const TIN* __restrict__ X, const float* __restrict__ W,
                  const float* __restrict__ bias, TOUT* __restrict__ Y) {
    extern __shared__ __align__(16) char smem[];
    constexpr bool XBF = (sizeof(TIN) == 2);
    constexpr int WOFF = XBF ? 16384 : 32768;

    const int t    = threadIdx.x;
    const int lane = t & 63;
    const int w    = t >> 6;
    const int c16  = lane & 15;
    const int g    = (lane >> 4) & 3;
    const int p    = lane & 3;
    const int G    = lane >> 2;

    const int n0 = blockIdx.x * 128;
    const int e0 = blockIdx.y * 128;
    const int b  = blockIdx.z;
    const size_t plane = (size_t)b * DDIM * NNN;

    f32x4 acc[8];
    #pragma unroll
    for (int nf = 0; nf < 8; ++nf) acc[nf] = f32x4{0.f, 0.f, 0.f, 0.f};

    #pragma unroll
    for (int ft = 0; ft < 4; ++ft) {
        const int f0 = ft * 64;
        if (ft) __syncthreads();
        #pragma unroll
        for (int it = 0; it < 4; ++it) {
            int chunk = w + 8 * it;
            int fch = chunk & 15, nh = chunk >> 4;
            float v[4];
            ldx4(&X[plane + (size_t)(f0 + fch * 4 + p) * NNN + n0 + nh * 64 + G * 4], v);
            xpose4(v, p);
            int nl = nh * 64 + G * 4 + p;
            int base = nl * 128 + ((fch * 8) ^ ((nl & 7) << 4));
            if constexpr (XBF) split1_store(smem + base, v);
            else               split2_store(smem + base, v);
        }
        #pragma unroll
        for (int it = 0; it < 4; ++it) {
            int idx = t + 512 * it;
            int el = idx >> 4, fq = idx & 15;
            float v[4];
            const float4 f4 = *(const float4*)&W[(size_t)(e0 + el) * DDIM + f0 + fq * 4];
            v[0] = f4.x; v[1] = f4.y; v[2] = f4.z; v[3] = f4.w;
            int base = WOFF + el * 128 + ((fq * 8) ^ ((el & 7) << 4));
            split2_store(smem + base, v);
        }
        __syncthreads();

        const int ew = w * 16;
        short8 a0[2], a1[2];
        #pragma unroll
        for (int ks = 0; ks < 2; ++ks) {
            int off = WOFF + (ew + c16) * 128
                    + ((ks * 64 + g * 16) ^ ((c16 & 7) << 4));
            a0[ks] = *(const short8*)(smem + off);
            a1[ks] = *(const short8*)(smem + off + 16384);
        }
        #pragma unroll
        for (int nf = 0; nf < 8; ++nf) {
            #pragma unroll
            for (int ks = 0; ks < 2; ++ks) {
                int off = (nf * 16 + c16) * 128
                        + ((ks * 64 + g * 16) ^ ((c16 & 7) << 4));
                short8 b0 = *(const short8*)(smem + off);
                f32x4 a = acc[nf];
                a = __builtin_amdgcn_mfma_f32_16x16x32_bf16(a0[ks], b0, a, 0, 0, 0);
                if constexpr (!XBF) {
                    short8 b1 = *(const short8*)(smem + off + 16384);
                    a = __builtin_amdgcn_mfma_f32_16x16x32_bf16(a0[ks], b1, a, 0, 0, 0);
                }
                a = __builtin_amdgcn_mfma_f32_16x16x32_bf16(a1[ks], b0, a, 0, 0, 0);
                acc[nf] = a;
            }
        }
    }

    const int ew = w * 16;
    float bs[4];
    #pragma unroll
    for (int r = 0; r < 4; ++r) bs[r] = bias[e0 + ew + g * 4 + r];
    #pragma unroll
    for (int nf = 0; nf < 8; ++nf) {
        #pragma unroll
        for (int r = 0; r < 4; ++r) {
            size_t off = plane + (size_t)(e0 + ew + g * 4 + r) * NNN + n0 + nf * 16 + c16;
            float val = acc[nf][r] + bs[r];
            if constexpr (sizeof(TOUT) == 4) Y[off] = val;
            else                             *(unsigned short*)&Y[off] = f2bf(val);
        }
    }
}

// ---------------------------------------------------------------------------
extern "C" void kernel_launch(void* const* d_in, const int* in_sizes, int n_in,
                              void* d_out, int out_size, void* d_ws, size_t ws_size,
                              hipStream_t stream) {
    const float* x   = (const float*)d_in[0];
    const float* src = (const float*)d_in[1];
    const float* Wq  = (const float*)d_in[2];
    const float* bq  = (const float*)d_in[3];
    const float* Wk  = (const float*)d_in[4];
    const float* bk  = (const float*)d_in[5];
    const float* Wv  = (const float*)d_in[6];
    const float* bv  = (const float*)d_in[7];
    const float* Wm  = (const float*)d_in[8];
    const float* bm  = (const float*)d_in[9];
    const int*   kp  = (const int*)d_in[10];
    float* out = (float*)d_out;

    char* ws = (char*)d_ws;
    const size_t F32PLANE  = 33554432;      // f32 [b,e,n]
    const size_t BF16PLANE = 16777216;      // bf16 plane

    float* qf = (float*)(ws);
    float* kf = (float*)(ws + F32PLANE);
    bf16*  vb = (bf16*)(ws + 2 * F32PLANE);
    bf16*  ob = (bf16*)(ws + 2 * F32PLANE + BF16PLANE);

    hipFuncSetAttribute((const void*)(projm_kernel<float, bf16>),
                        hipFuncAttributeMaxDynamicSharedMemorySize, 65536);
    hipFuncSetAttribute((const void*)(projm_kernel<bf16, float>),
                        hipFuncAttributeMaxDynamicSharedMemorySize, 49152);
    hipFuncSetAttribute((const void*)attn5_kernel,
                        hipFuncAttributeMaxDynamicSharedMemorySize, 32768);

    dim3 pgrid(NNN / 128, DDIM / 64, BB);   // (2, 4, 128)
    dim3 mgrid(2, 2, BB);

    hipLaunchKernelGGL(proj_kernel, pgrid, dim3(256), 0, stream,
                       x,   Wq, bq, qf);
    hipLaunchKernelGGL(proj_kernel, pgrid, dim3(256), 0, stream,
                       src, Wk, bk, kf);
    hipLaunchKernelGGL((projm_kernel<float, bf16>), mgrid, dim3(512), 65536, stream,
                       src, Wv, bv, vb);
    hipLaunchKernelGGL(attn5_kernel, dim3(2048), dim3(256), 32768, stream,
                       qf, kf, vb, ob, kp);
    hipLaunchKernelGGL((projm_kernel<bf16, float>), mgrid, dim3(512), 49152, stream,
                       ob, Wm, bm, out);
}

// Round 16
// 242.603 us; speedup vs baseline: 1.0272x; 1.0272x over previous
//
#include <hip/hip_runtime.h>
#include <hip/hip_bf16.h>

#define BB   128
#define DDIM 256
#define HH   4
#define NNN  256
#define MMM  256

typedef __hip_bfloat16 bf16;
typedef short  short8   __attribute__((ext_vector_type(8)));
typedef unsigned short ushort8_t __attribute__((ext_vector_type(8)));
typedef float  f32x4    __attribute__((ext_vector_type(4)));
typedef float  f32x2    __attribute__((ext_vector_type(2)));

// ---------------- helpers ----------------
__device__ __forceinline__ unsigned short f2bf(float x) {       // RNE f32->bf16
    unsigned u = __builtin_bit_cast(unsigned, x);
    u += 0x7FFFu + ((u >> 16) & 1u);
    return (unsigned short)(u >> 16);
}
__device__ __forceinline__ float bf2f(unsigned short b) {
    unsigned u = ((unsigned)b) << 16;
    return __builtin_bit_cast(float, u);
}

// transpose a 4x4 f32 tile held across 4 consecutive lanes (p = lane&3).
__device__ __forceinline__ void xpose4(float v[4], const int p) {
    float ta = __shfl_xor((p & 1) ? v[0] : v[1], 1, 64);
    float tb = __shfl_xor((p & 1) ? v[2] : v[3], 1, 64);
    float u0 = (p & 1) ? ta : v[0];
    float u1 = (p & 1) ? v[1] : ta;
    float u2 = (p & 1) ? tb : v[2];
    float u3 = (p & 1) ? v[3] : tb;
    float tc = __shfl_xor((p & 2) ? u0 : u2, 2, 64);
    float td = __shfl_xor((p & 2) ? u1 : u3, 2, 64);
    v[0] = (p & 2) ? tc : u0;
    v[1] = (p & 2) ? td : u1;
    v[2] = (p & 2) ? u2 : tc;
    v[3] = (p & 2) ? u3 : td;
}

// 3-level bf16 split to 3 planes 8192 B apart (attn Q/K staging)
__device__ __forceinline__ void split3_store8k(char* dst, const float v[4]) {
    unsigned short h[4], m[4], l[4];
    #pragma unroll
    for (int i = 0; i < 4; ++i) {
        h[i] = f2bf(v[i]);
        float r1 = v[i] - bf2f(h[i]);
        m[i] = f2bf(r1);
        float r2 = r1 - bf2f(m[i]);
        l[i] = f2bf(r2);
    }
    uint2 hp, mp, lp;
    hp.x = (unsigned)h[0] | ((unsigned)h[1] << 16);
    hp.y = (unsigned)h[2] | ((unsigned)h[3] << 16);
    mp.x = (unsigned)m[0] | ((unsigned)m[1] << 16);
    mp.y = (unsigned)m[2] | ((unsigned)m[3] << 16);
    lp.x = (unsigned)l[0] | ((unsigned)l[1] << 16);
    lp.y = (unsigned)l[2] | ((unsigned)l[3] << 16);
    *(uint2*)dst = hp;
    *(uint2*)(dst + 8192) = mp;
    *(uint2*)(dst + 16384) = lp;
}

// 2-plane split (planes 16384 B apart): hi/mid   (projm)
__device__ __forceinline__ void split2_store(char* dst, const float v[4]) {
    unsigned short h[4], m[4];
    #pragma unroll
    for (int i = 0; i < 4; ++i) {
        h[i] = f2bf(v[i]);
        float r1 = v[i] - bf2f(h[i]);
        m[i] = f2bf(r1);
    }
    uint2 hp, mp;
    hp.x = (unsigned)h[0] | ((unsigned)h[1] << 16);
    hp.y = (unsigned)h[2] | ((unsigned)h[3] << 16);
    mp.x = (unsigned)m[0] | ((unsigned)m[1] << 16);
    mp.y = (unsigned)m[2] | ((unsigned)m[3] << 16);
    *(uint2*)dst = hp;
    *(uint2*)(dst + 16384) = mp;
}

// single-plane bf16 store (exact when v came from bf16)
__device__ __forceinline__ void split1_store(char* dst, const float v[4]) {
    uint2 hp;
    hp.x = (unsigned)f2bf(v[0]) | ((unsigned)f2bf(v[1]) << 16);
    hp.y = (unsigned)f2bf(v[2]) | ((unsigned)f2bf(v[3]) << 16);
    *(uint2*)dst = hp;
}

__device__ __forceinline__ void ldx4(const float* p, float v[4]) {
    const float4 f = *(const float4*)p;
    v[0] = f.x; v[1] = f.y; v[2] = f.z; v[3] = f.w;
}
__device__ __forceinline__ void ldx4(const bf16* p, float v[4]) {
    uint2 u = *(const uint2*)p;
    v[0] = bf2f((unsigned short)(u.x & 0xFFFF));
    v[1] = bf2f((unsigned short)(u.x >> 16));
    v[2] = bf2f((unsigned short)(u.y & 0xFFFF));
    v[3] = bf2f((unsigned short)(u.y >> 16));
}

__device__ __forceinline__ float gmax16(float v) {
    v = fmaxf(v, __shfl_xor(v, 1, 64));
    v = fmaxf(v, __shfl_xor(v, 2, 64));
    v = fmaxf(v, __shfl_xor(v, 4, 64));
    v = fmaxf(v, __shfl_xor(v, 8, 64));
    return v;
}
__device__ __forceinline__ float gsum16(float v) {
    v += __shfl_xor(v, 1, 64);
    v += __shfl_xor(v, 2, 64);
    v += __shfl_xor(v, 4, 64);
    v += __shfl_xor(v, 8, 64);
    return v;
}

// bitonic sort of 16 values, DESCENDING, fully static (80 compare-exchanges).
__device__ __forceinline__ void sort16_desc(float w[16]) {
    #pragma unroll
    for (int k = 2; k <= 16; k <<= 1) {
        #pragma unroll
        for (int j = k >> 1; j > 0; j >>= 1) {
            #pragma unroll
            for (int i = 0; i < 16; ++i) {
                const int l = i ^ j;
                if (l > i) {
                    const bool dmax = ((i & k) == 0);   // descending network
                    float mx = fmaxf(w[i], w[l]);
                    float mn = fminf(w[i], w[l]);
                    w[i] = dmax ? mx : mn;
                    w[l] = dmax ? mn : mx;
                }
            }
        }
    }
}

// ---------------------------------------------------------------------------
// Fused Q+K projection: ONE launch, grid (2,4,256). z<128 -> Q (x,Wq,bq->qf),
// z>=128 -> K (src,Wk,bk->kf). Body verbatim round-12..15 green proj_kernel:
// per output element sequential packed-f32x2 FMA over f=0..255 -> outputs
// bitwise identical to two separate launches.
// ---------------------------------------------------------------------------
__global__ __launch_bounds__(256)
void projqk2_kernel(const float* __restrict__ x, const float* __restrict__ src,
                    const float* __restrict__ Wq, const float* __restrict__ bq,
                    const float* __restrict__ Wk, const float* __restrict__ bk,
                    float* __restrict__ qf, float* __restrict__ kf) {
    __shared__ float Wt[32][68];    // [f_local][e_local 0..63]
    __shared__ float Xt[32][132];   // [f_local][n_local 0..127]

    const int zz = blockIdx.z;
    const bool isK = (zz >= BB);
    const int b = isK ? (zz - BB) : zz;
    const float* __restrict__ X    = isK ? src : x;
    const float* __restrict__ W    = isK ? Wk  : Wq;
    const float* __restrict__ bias = isK ? bk  : bq;
    float* __restrict__ Y          = isK ? kf  : qf;

    const int t  = threadIdx.x;
    const int tx = t & 31;          // n sub-tile: 4n at tx*4
    const int ty = t >> 5;          // e sub-tile: 8e at ty*8
    const int n0 = blockIdx.x * 128;
    const int e0 = blockIdx.y * 64;
    const size_t plane = (size_t)b * DDIM * NNN;

    f32x2 acc2[8][2];
    #pragma unroll
    for (int i = 0; i < 8; ++i) {
        acc2[i][0] = f32x2{0.f, 0.f};
        acc2[i][1] = f32x2{0.f, 0.f};
    }

    for (int f0 = 0; f0 < DDIM; f0 += 32) {
        #pragma unroll
        for (int i = 0; i < 8; ++i) {
            int idx = t + i * 256;          // 0..2047
            int fl = idx & 31, el = idx >> 5;
            Wt[fl][el] = W[(size_t)(e0 + el) * DDIM + f0 + fl];
        }
        #pragma unroll
        for (int i = 0; i < 4; ++i) {
            int idx = t + i * 256;          // 0..1023
            int fl = idx >> 5, nl4 = idx & 31;
            *(float4*)&Xt[fl][nl4 * 4] =
                *(const float4*)&X[plane + (size_t)(f0 + fl) * NNN + n0 + nl4 * 4];
        }
        __syncthreads();

        #pragma unroll
        for (int ff = 0; ff < 32; ++ff) {
            const float4 av0 = *(const float4*)&Wt[ff][ty * 8];
            const float4 av1 = *(const float4*)&Wt[ff][ty * 8 + 4];
            const float4 bv  = *(const float4*)&Xt[ff][tx * 4];
            const float a[8] = {av0.x, av0.y, av0.z, av0.w, av1.x, av1.y, av1.z, av1.w};
            const f32x2 c0 = {bv.x, bv.y};
            const f32x2 c1 = {bv.z, bv.w};
            #pragma unroll
            for (int i2 = 0; i2 < 8; ++i2) {
                const f32x2 aa = {a[i2], a[i2]};
                acc2[i2][0] = __builtin_elementwise_fma(aa, c0, acc2[i2][0]);
                acc2[i2][1] = __builtin_elementwise_fma(aa, c1, acc2[i2][1]);
            }
        }
        __syncthreads();
    }

    #pragma unroll
    for (int i2 = 0; i2 < 8; ++i2) {
        const int e = e0 + ty * 8 + i2;
        const float bs = bias[e];
        const size_t off = plane + (size_t)e * NNN + n0 + tx * 4;
        float4 o;
        o.x = acc2[i2][0].x + bs; o.y = acc2[i2][0].y + bs;
        o.z = acc2[i2][1].x + bs; o.w = acc2[i2][1].y + bs;
        *(float4*)&Y[off] = o;
    }
}

// ---------------------------------------------------------------------------
// attn5: fused attention (round-15 green, verbatim). K staged in-kernel from
// plain f32 [b,e,n] via xpose4+split3. 4 waves, 32 KB LDS, 4 blocks/CU.
// ---------------------------------------------------------------------------
__global__ __launch_bounds__(256, 4)
void attn5_kernel(const float* __restrict__ qf, const float* __restrict__ kf,
                  const bf16* __restrict__ vb, bf16* __restrict__ ob,
                  const int* __restrict__ kptr) {
    extern __shared__ __align__(16) char smem[];

    const int t    = threadIdx.x;
    const int lane = t & 63;
    const int w    = t >> 6;
    const int g    = lane >> 4;
    const int c16  = lane & 15;

    const int i    = blockIdx.x;
    const int work = (i & 7) * 256 + (i >> 3);
    const int bx = work & 3;
    const int h  = (work >> 2) & 3;
    const int b  = work >> 4;
    const int n0 = bx * 64;

    const size_t planeF = (size_t)b * DDIM * NNN;
    const size_t planeV = (size_t)b * DDIM * MMM;

    int kk = kptr[0];
    kk = kk < 1 ? 1 : (kk > MMM ? MMM : kk);

    // ---- stage Q from [b,e,n]: strided load, x0.125, xpose4, split3 ----
    {
        const int p = lane & 3, G = lane >> 2;
        #pragma unroll
        for (int it = 0; it < 4; ++it) {
            int dch = w + 4 * it;               // 0..15
            int drow = dch * 4 + p;
            float v[4];
            const float4 f4 = *(const float4*)&qf[planeF + (size_t)(drow * HH + h) * NNN + n0 + G * 4];
            v[0] = f4.x * 0.125f; v[1] = f4.y * 0.125f;
            v[2] = f4.z * 0.125f; v[3] = f4.w * 0.125f;
            xpose4(v, p);
            int nl = G * 4 + p;                 // 0..63
            int base = nl * 128 + ((dch * 8) ^ ((nl & 7) << 4));
            split3_store8k(smem + base, v);
        }
    }
    __syncthreads();

    // ---- Q A-fragments -> regs ----
    short8 qh[2], qm[2], ql[2];
    #pragma unroll
    for (int ks = 0; ks < 2; ++ks) {
        int nl = w * 16 + c16;
        int off = nl * 128 + ((ks * 64 + g * 16) ^ ((nl & 7) << 4));
        qh[ks] = *(const short8*)(smem + off);
        qm[ks] = *(const short8*)(smem + 8192 + off);
        ql[ks] = *(const short8*)(smem + 16384 + off);
    }
    __syncthreads();    // Q LDS region free for K

    // ---- scores ----
    f32x4 acc[16];
    #pragma unroll
    for (int m = 0; m < 16; ++m) acc[m] = f32x4{0.f, 0.f, 0.f, 0.f};

    #pragma unroll
    for (int tt = 0; tt < 4; ++tt) {
        if (tt) __syncthreads();            // prev tt's frag reads done
        // stage K tile [64m][64d] from f32 [b,e,n]: xpose4 + split3
        {
            const int p = lane & 3, G = lane >> 2;
            #pragma unroll
            for (int it = 0; it < 4; ++it) {
                int dch = w + 4 * it;           // 0..15
                int drow = dch * 4 + p;
                int mcol = tt * 64 + G * 4;
                float v[4];
                const float4 f4 = *(const float4*)&kf[planeF + (size_t)(drow * HH + h) * MMM + mcol];
                v[0] = f4.x; v[1] = f4.y; v[2] = f4.z; v[3] = f4.w;
                xpose4(v, p);
                int ml = G * 4 + p;             // tile-local m 0..63
                int base = ml * 128 + ((dch * 8) ^ ((ml & 7) << 4));
                split3_store8k(smem + base, v);
            }
        }
        __syncthreads();

        #pragma unroll
        for (int mf = 0; mf < 4; ++mf) {
            #pragma unroll
            for (int ks = 0; ks < 2; ++ks) {
                int ml = mf * 16 + c16;
                int off = ml * 128 + ((ks * 64 + g * 16) ^ ((ml & 7) << 4));
                short8 bh_ = *(const short8*)(smem + off);
                short8 bm_ = *(const short8*)(smem + 8192 + off);
                short8 bl_ = *(const short8*)(smem + 16384 + off);
                f32x4 a = acc[tt * 4 + mf];
                a = __builtin_amdgcn_mfma_f32_16x16x32_bf16(qh[ks], bh_, a, 0, 0, 0);
                a = __builtin_amdgcn_mfma_f32_16x16x32_bf16(qh[ks], bm_, a, 0, 0, 0);
                a = __builtin_amdgcn_mfma_f32_16x16x32_bf16(qm[ks], bh_, a, 0, 0, 0);
                a = __builtin_amdgcn_mfma_f32_16x16x32_bf16(qm[ks], bm_, a, 0, 0, 0);
                a = __builtin_amdgcn_mfma_f32_16x16x32_bf16(qh[ks], bl_, a, 0, 0, 0);
                a = __builtin_amdgcn_mfma_f32_16x16x32_bf16(ql[ks], bh_, a, 0, 0, 0);
                acc[tt * 4 + mf] = a;
            }
        }
    }
    __syncthreads();    // K reads done: P region free

    // ---- top-k thresholds via per-lane descending sort + leader shift-pop ----
    float thr[4], rmx[4];
    #pragma unroll
    for (int r = 0; r < 4; ++r) {
        float s[16];
        #pragma unroll
        for (int mf = 0; mf < 16; ++mf) s[mf] = acc[mf][r];
        sort16_desc(s);
        float gm = gmax16(s[0]);
        rmx[r] = gm;
        for (int it = 1; it < kk; ++it) {
            unsigned long long bal = __ballot(s[0] == gm);
            unsigned gmask = (unsigned)((bal >> (g * 16)) & 0xFFFFull);
            int leader = __builtin_ctz(gmask);
            bool hit = (c16 == leader);
            #pragma unroll
            for (int j = 0; j < 15; ++j) s[j] = hit ? s[j + 1] : s[j];
            s[15] = hit ? -INFINITY : s[15];
            gm = gmax16(s[0]);
        }
        thr[r] = gm;
    }

    // ---- softmax (in regs) -> P [64][256] @0 ----
    #pragma unroll
    for (int mf = 0; mf < 16; ++mf) {
        #pragma unroll
        for (int r = 0; r < 4; ++r) {
            float a = acc[mf][r];
            acc[mf][r] = (a >= thr[r]) ? __expf(a - rmx[r]) : 0.f;
        }
    }
    float inv_[4];
    #pragma unroll
    for (int r = 0; r < 4; ++r) {
        float s = ((acc[0][r] + acc[1][r]) + (acc[2][r] + acc[3][r]))
                + ((acc[4][r] + acc[5][r]) + (acc[6][r] + acc[7][r]))
                + ((acc[8][r] + acc[9][r]) + (acc[10][r] + acc[11][r]))
                + ((acc[12][r] + acc[13][r]) + (acc[14][r] + acc[15][r]));
        s = gsum16(s);
        inv_[r] = 1.0f / s;
    }
    #pragma unroll
    for (int mf = 0; mf < 16; ++mf) {
        #pragma unroll
        for (int r = 0; r < 4; ++r) {
            int row = w * 16 + g * 4 + r;
            int m2  = (mf * 16 + c16) * 2;
            int off = row * 512 + (m2 ^ ((row & 7) << 4));
            *(unsigned short*)(smem + off) = f2bf(acc[mf][r] * inv_[r]);
        }
    }
    __syncthreads();

    // ---- PV: P from LDS, V B-frags DIRECT from global ----
    f32x4 o[4];
    #pragma unroll
    for (int df = 0; df < 4; ++df) o[df] = f32x4{0.f, 0.f, 0.f, 0.f};

    #pragma unroll
    for (int half = 0; half < 2; ++half) {
        short8 pa[4];
        #pragma unroll
        for (int ks = 0; ks < 4; ++ks) {
            int row = w * 16 + c16;
            int off = row * 512 + ((half * 256 + ks * 64 + g * 16) ^ ((row & 7) << 4));
            pa[ks] = *(const short8*)(smem + off);
        }
        #pragma unroll
        for (int df = 0; df < 4; ++df) {
            int d = df * 16 + c16;
            const bf16* vrow = vb + planeV + (size_t)(d * HH + h) * MMM + half * 128;
            f32x4 o_ = o[df];
            #pragma unroll
            for (int ks = 0; ks < 4; ++ks) {
                short8 vv = *(const short8*)(vrow + ks * 32 + g * 8);
                o_ = __builtin_amdgcn_mfma_f32_16x16x32_bf16(pa[ks], vv, o_, 0, 0, 0);
            }
            o[df] = o_;
        }
    }
    __syncthreads();    // P reads done; out region free

    // ---- out: frags -> [64d][64n] @0 -> global [channel][n] ----
    #pragma unroll
    for (int df = 0; df < 4; ++df)
        #pragma unroll
        for (int r = 0; r < 4; ++r) {
            int d  = df * 16 + c16;
            int nl = w * 16 + g * 4 + r;
            int off = d * 128 + ((nl * 2) ^ ((d & 7) << 4));
            *(unsigned short*)(smem + off) = f2bf(o[df][r]);
        }
    __syncthreads();
    #pragma unroll
    for (int it = 0; it < 2; ++it) {
        int idx = t + it * 256;                 // 0..511
        int d = idx >> 3, ch = idx & 7;
        int off = d * 128 + ((ch * 16) ^ ((d & 7) << 4));
        ushort8_t val = *(const ushort8_t*)(smem + off);
        *(ushort8_t*)&ob[planeV + (size_t)(d * HH + h) * NNN + n0 + ch * 8] = val;
    }
}

// ---------------------------------------------------------------------------
// MFMA projection (VALUE paths). Round-12..15 green, verbatim.
// ---------------------------------------------------------------------------
template <typename TIN, typename TOUT>
__global__ __launch_bounds__(512, 2)
void projm_kernel(const TIN* __restrict__ X, const float* __restrict__ W,
                  const float* __restrict__ bias, TOUT* __restrict__ Y) {
    extern __shared__ __align__(16) char smem[];
    constexpr bool XBF = (sizeof(TIN) == 2);
    constexpr int WOFF = XBF ? 16384 : 32768;

    const int t    = threadIdx.x;
    const int lane = t & 63;
    const int w    = t >> 6;
    const int c16  = lane & 15;
    const int g    = (lane >> 4) & 3;
    const int p    = lane & 3;
    const int G    = lane >> 2;

    const int n0 = blockIdx.x * 128;
    const int e0 = blockIdx.y * 128;
    const int b  = blockIdx.z;
    const size_t plane = (size_t)b * DDIM * NNN;

    f32x4 acc[8];
    #pragma unroll
    for (int nf = 0; nf < 8; ++nf) acc[nf] = f32x4{0.f, 0.f, 0.f, 0.f};

    #pragma unroll
    for (int ft = 0; ft < 4; ++ft) {
        const int f0 = ft * 64;
        if (ft) __syncthreads();
        #pragma unroll
        for (int it = 0; it < 4; ++it) {
            int chunk = w + 8 * it;
            int fch = chunk & 15, nh = chunk >> 4;
            float v[4];
            ldx4(&X[plane + (size_t)(f0 + fch * 4 + p) * NNN + n0 + nh * 64 + G * 4], v);
            xpose4(v, p);
            int nl = nh * 64 + G * 4 + p;
            int base = nl * 128 + ((fch * 8) ^ ((nl & 7) << 4));
            if constexpr (XBF) split1_store(smem + base, v);
            else               split2_store(smem + base, v);
        }
        #pragma unroll
        for (int it = 0; it < 4; ++it) {
            int idx = t + 512 * it;
            int el = idx >> 4, fq = idx & 15;
            float v[4];
            const float4 f4 = *(const float4*)&W[(size_t)(e0 + el) * DDIM + f0 + fq * 4];
            v[0] = f4.x; v[1] = f4.y; v[2] = f4.z; v[3] = f4.w;
            int base = WOFF + el * 128 + ((fq * 8) ^ ((el & 7) << 4));
            split2_store(smem + base, v);
        }
        __syncthreads();

        const int ew = w * 16;
        short8 a0[2], a1[2];
        #pragma unroll
        for (int ks = 0; ks < 2; ++ks) {
            int off = WOFF + (ew + c16) * 128
                    + ((ks * 64 + g * 16) ^ ((c16 & 7) << 4));
            a0[ks] = *(const short8*)(smem + off);
            a1[ks] = *(const short8*)(smem + off + 16384);
        }
        #pragma unroll
        for (int nf = 0; nf < 8; ++nf) {
            #pragma unroll
            for (int ks = 0; ks < 2; ++ks) {
                int off = (nf * 16 + c16) * 128
                        + ((ks * 64 + g * 16) ^ ((c16 & 7) << 4));
                short8 b0 = *(const short8*)(smem + off);
                f32x4 a = acc[nf];
                a = __builtin_amdgcn_mfma_f32_16x16x32_bf16(a0[ks], b0, a, 0, 0, 0);
                if constexpr (!XBF) {
                    short8 b1 = *(const short8*)(smem + off + 16384);
                    a = __builtin_amdgcn_mfma_f32_16x16x32_bf16(a0[ks], b1, a, 0, 0, 0);
                }
                a = __builtin_amdgcn_mfma_f32_16x16x32_bf16(a1[ks], b0, a, 0, 0, 0);
                acc[nf] = a;
            }
        }
    }

    const int ew = w * 16;
    float bs[4];
    #pragma unroll
    for (int r = 0; r < 4; ++r) bs[r] = bias[e0 + ew + g * 4 + r];
    #pragma unroll
    for (int nf = 0; nf < 8; ++nf) {
        #pragma unroll
        for (int r = 0; r < 4; ++r) {
            size_t off = plane + (size_t)(e0 + ew + g * 4 + r) * NNN + n0 + nf * 16 + c16;
            float val = acc[nf][r] + bs[r];
            if constexpr (sizeof(TOUT) == 4) Y[off] = val;
            else                             *(unsigned short*)&Y[off] = f2bf(val);
        }
    }
}

// ---------------------------------------------------------------------------
extern "C" void kernel_launch(void* const* d_in, const int* in_sizes, int n_in,
                              void* d_out, int out_size, void* d_ws, size_t ws_size,
                              hipStream_t stream) {
    const float* x   = (const float*)d_in[0];
    const float* src = (const float*)d_in[1];
    const float* Wq  = (const float*)d_in[2];
    const float* bq  = (const float*)d_in[3];
    const float* Wk  = (const float*)d_in[4];
    const float* bk  = (const float*)d_in[5];
    const float* Wv  = (const float*)d_in[6];
    const float* bv  = (const float*)d_in[7];
    const float* Wm  = (const float*)d_in[8];
    const float* bm  = (const float*)d_in[9];
    const int*   kp  = (const int*)d_in[10];
    float* out = (float*)d_out;

    char* ws = (char*)d_ws;
    const size_t F32PLANE  = 33554432;      // f32 [b,e,n]
    const size_t BF16PLANE = 16777216;      // bf16 plane

    float* qf = (float*)(ws);
    float* kf = (float*)(ws + F32PLANE);
    bf16*  vb = (bf16*)(ws + 2 * F32PLANE);
    bf16*  ob = (bf16*)(ws + 2 * F32PLANE + BF16PLANE);

    hipFuncSetAttribute((const void*)(projm_kernel<float, bf16>),
                        hipFuncAttributeMaxDynamicSharedMemorySize, 65536);
    hipFuncSetAttribute((const void*)(projm_kernel<bf16, float>),
                        hipFuncAttributeMaxDynamicSharedMemorySize, 49152);
    hipFuncSetAttribute((const void*)attn5_kernel,
                        hipFuncAttributeMaxDynamicSharedMemorySize, 32768);

    dim3 qkgrid(NNN / 128, DDIM / 64, 2 * BB);  // (2, 4, 256): Q + K in one launch
    dim3 mgrid(2, 2, BB);

    hipLaunchKernelGGL(projqk2_kernel, qkgrid, dim3(256), 0, stream,
                       x, src, Wq, bq, Wk, bk, qf, kf);
    hipLaunchKernelGGL((projm_kernel<float, bf16>), mgrid, dim3(512), 65536, stream,
                       src, Wv, bv, vb);
    hipLaunchKernelGGL(attn5_kernel, dim3(2048), dim3(256), 32768, stream,
                       qf, kf, vb, ob, kp);
    hipLaunchKernelGGL((projm_kernel<bf16, float>), mgrid, dim3(512), 49152, stream,
                       ob, Wm, bm, out);
}